// Round 1
// baseline (452.999 us; speedup 1.0000x reference)
//
#include <hip/hip_runtime.h>
#include <cstddef>

#define HYP_C   0.1f
#define SQRT_C  0.31622776601683794f
#define CLIP_R  2.3f
#define MRG     0.1f
#define NPROX   256
#define DIM     128

// workspace layout (float offsets)
#define OFF_LH   0         // lh row-major      [256][128]
#define OFF_LHT  32768     // lh transposed     [128][256]
#define OFF_LN2  65536     // ||lh_m||^2        [256]
#define OFF_D1   65792     // dist(z, lh)       [1024][256]
#define OFF_D2   327936    // dist(lh, lh)      [256][256]
#define OFF_D3   393472    // dist(t, lh)       [1024][256]
// total floats: 655616  (~2.62 MB)

// ---------------------------------------------------------------------------
// Kernel A: to_poincare(lcas) -> lh, lhT, ln2 ; also zero d_out
// grid = 256 blocks (one per proxy row), block = 128 threads
// ---------------------------------------------------------------------------
__global__ __launch_bounds__(128)
void to_poincare_kernel(const float* __restrict__ lcas,
                        float* __restrict__ ws,
                        float* __restrict__ out)
{
    const int row = blockIdx.x;
    const int k   = threadIdx.x;
    if (row == 0 && k == 0) out[0] = 0.0f;

    float v  = lcas[row * DIM + k];
    float ss = v * v;
    #pragma unroll
    for (int off = 32; off >= 1; off >>= 1)
        ss += __shfl_xor(ss, off, 64);
    __shared__ float wpart[2];
    if ((k & 63) == 0) wpart[k >> 6] = ss;
    __syncthreads();
    const float sumsq = wpart[0] + wpart[1];

    // clip to radius CLIP_R
    const float s1 = sqrtf(sumsq);
    const float xn = s1 + 1e-5f;
    const float f1 = fminf(1.0f, CLIP_R / xn);
    // expmap0
    const float xn2 = fmaxf(f1 * s1, 1e-5f);
    const float th  = tanhf(SQRT_C * xn2);
    const float f2  = th / (SQRT_C * xn2);
    // project
    const float nr      = fmaxf(f2 * f1 * s1, 1e-5f);
    const float maxnorm = (1.0f - 1e-3f) / SQRT_C;
    const float f3      = (nr > maxnorm) ? (maxnorm / nr) : 1.0f;

    const float f  = f3 * f2 * f1;
    const float lv = f * v;
    ws[OFF_LH  + row * DIM + k]  = lv;
    ws[OFF_LHT + k * NPROX + row] = lv;
    if (k == 0) ws[OFF_LN2 + row] = f * f * sumsq;
}

// ---------------------------------------------------------------------------
// Kernel B: hyperbolic distance matrix  D[n][m] = dist(X_n, lh_m)
// 4 rows per block; block = 256 threads (thread m owns column m)
// ---------------------------------------------------------------------------
__global__ __launch_bounds__(256)
void dist_kernel(const float* __restrict__ X,
                 const float* __restrict__ lhT,
                 const float* __restrict__ ln2,
                 float* __restrict__ Dout)
{
    __shared__ float xs[4][DIM];
    __shared__ float sx2[4];
    const int row0 = blockIdx.x * 4;

    for (int idx = threadIdx.x; idx < 4 * DIM; idx += 256)
        xs[idx / DIM][idx % DIM] = X[row0 * DIM + idx];
    __syncthreads();

    const int wid  = threadIdx.x >> 6;
    const int lane = threadIdx.x & 63;
    {   // wave `wid` reduces ||x_row(wid)||^2
        float a = xs[wid][lane];
        float b = xs[wid][lane + 64];
        float s = a * a + b * b;
        #pragma unroll
        for (int off = 32; off >= 1; off >>= 1)
            s += __shfl_xor(s, off, 64);
        if (lane == 0) sx2[wid] = s;
    }
    __syncthreads();

    const int m = threadIdx.x;
    float dot0 = 0.f, dot1 = 0.f, dot2 = 0.f, dot3 = 0.f;
    #pragma unroll 4
    for (int k = 0; k < DIM; ++k) {
        const float lv = lhT[k * NPROX + m];   // coalesced
        dot0 = fmaf(xs[0][k], lv, dot0);
        dot1 = fmaf(xs[1][k], lv, dot1);
        dot2 = fmaf(xs[2][k], lv, dot2);
        dot3 = fmaf(xs[3][k], lv, dot3);
    }

    const float y2 = ln2[m];
    float dots[4] = {dot0, dot1, dot2, dot3};
    #pragma unroll
    for (int r = 0; r < 4; ++r) {
        const float x2 = sx2[r];
        const float xy = -dots[r];
        const float a  = 1.0f + 2.0f * HYP_C * xy + HYP_C * y2;
        const float b  = 1.0f - HYP_C * x2;
        const float denom  = 1.0f + 2.0f * HYP_C * xy + HYP_C * HYP_C * x2 * y2;
        const float num_sq = a * a * x2 + 2.0f * a * b * xy + b * b * y2;
        const float nrm = sqrtf(fmaxf(num_sq, 1e-12f)) / fabsf(denom + 1e-5f);
        float u = SQRT_C * nrm;
        u = fminf(fmaxf(u, -1.0f + 1e-5f), 1.0f - 1e-5f);
        const float d = (2.0f / SQRT_C) * (0.5f * (log1pf(u) - log1pf(-u)));
        Dout[(size_t)(row0 + r) * NPROX + m] = d;
    }
}

// ---------------------------------------------------------------------------
// Kernel C: ghhc term. One wave (64 lanes) per triplet, grid-stride.
// p_ij / p_ijk collapse to argmax of (-max/tau + g)  (straight-through hard).
// ---------------------------------------------------------------------------
__global__ __launch_bounds__(256)
void ghhc_kernel(const float* __restrict__ D,
                 const int* __restrict__ trip,
                 const float* __restrict__ g,
                 int T, float invT,
                 float* __restrict__ out)
{
    const int lane = threadIdx.x & 63;
    const int gw   = (blockIdx.x * 256 + threadIdx.x) >> 6;
    const int nw   = gridDim.x * 4;
    float acc = 0.0f;

    for (int t = gw; t < T; t += nw) {
        const int i  = trip[t];
        const int j  = trip[T + t];
        const int kk = trip[2 * T + t];

        const float4 di = ((const float4*)(D + (size_t)i  * NPROX))[lane];
        const float4 dj = ((const float4*)(D + (size_t)j  * NPROX))[lane];
        const float4 dk = ((const float4*)(D + (size_t)kk * NPROX))[lane];
        const float4 g0 = ((const float4*)(g + (size_t)t * NPROX))[lane];
        const float4 g1 = ((const float4*)(g + ((size_t)T + t) * NPROX))[lane];

        const float m1x = fmaxf(di.x, dj.x), m1y = fmaxf(di.y, dj.y),
                    m1z = fmaxf(di.z, dj.z), m1w = fmaxf(di.w, dj.w);
        const int p0 = lane * 4;

        // argmax of s1 = -max_ij/tau + g0   (first index wins on ties)
        float s0 = (-m1x) / 0.1f + g0.x;
        float s1 = (-m1y) / 0.1f + g0.y;
        float s2 = (-m1z) / 0.1f + g0.z;
        float s3 = (-m1w) / 0.1f + g0.w;
        float bv = s0; int bi = p0;
        if (s1 > bv) { bv = s1; bi = p0 + 1; }
        if (s2 > bv) { bv = s2; bi = p0 + 2; }
        if (s3 > bv) { bv = s3; bi = p0 + 3; }
        #pragma unroll
        for (int off = 1; off < 64; off <<= 1) {
            const float ov = __shfl_xor(bv, off, 64);
            const int   oi = __shfl_xor(bi, off, 64);
            if (ov > bv || (ov == bv && oi < bi)) { bv = ov; bi = oi; }
        }
        const int A = bi;

        // argmax of s2 = -max_ijk/tau + g1
        const float m2x = fmaxf(dk.x, m1x), m2y = fmaxf(dk.y, m1y),
                    m2z = fmaxf(dk.z, m1z), m2w = fmaxf(dk.w, m1w);
        float u0 = (-m2x) / 0.1f + g1.x;
        float u1 = (-m2y) / 0.1f + g1.y;
        float u2 = (-m2z) / 0.1f + g1.z;
        float u3 = (-m2w) / 0.1f + g1.w;
        float cv = u0; int ci = p0;
        if (u1 > cv) { cv = u1; ci = p0 + 1; }
        if (u2 > cv) { cv = u2; ci = p0 + 2; }
        if (u3 > cv) { cv = u3; ci = p0 + 3; }
        #pragma unroll
        for (int off = 1; off < 64; off <<= 1) {
            const float ov = __shfl_xor(cv, off, 64);
            const int   oi = __shfl_xor(ci, off, 64);
            if (ov > cv || (ov == cv && oi < ci)) { cv = ov; ci = oi; }
        }
        const int B = ci;

        if (lane == 0 && A != B) {
            const float* Di = D + (size_t)i  * NPROX;
            const float* Dj = D + (size_t)j  * NPROX;
            const float* Dk = D + (size_t)kk * NPROX;
            const float hc = fmaxf(Di[A] - Di[B] + MRG, 0.0f)
                           + fmaxf(Dj[A] - Dj[B] + MRG, 0.0f)
                           + fmaxf(Dk[B] - Dk[A] + MRG, 0.0f);
            acc += hc;
        }
    }

    __shared__ float wsum[4];
    if (lane == 0) wsum[threadIdx.x >> 6] = acc;
    __syncthreads();
    if (threadIdx.x == 0)
        atomicAdd(out, (wsum[0] + wsum[1] + wsum[2] + wsum[3]) * invT);
}

// ---------------------------------------------------------------------------
extern "C" void kernel_launch(void* const* d_in, const int* in_sizes, int n_in,
                              void* d_out, int out_size, void* d_ws, size_t ws_size,
                              hipStream_t stream)
{
    const float* z_s  = (const float*)d_in[0];
    const float* t_s  = (const float*)d_in[1];
    // d_in[2] = y (unused)
    const float* lcas = (const float*)d_in[3];
    const int* trip1 = (const int*)d_in[4];
    const int* trip2 = (const int*)d_in[5];
    const int* trip3 = (const int*)d_in[6];
    const int* trip4 = (const int*)d_in[7];
    const float* g1 = (const float*)d_in[8];
    const float* g2 = (const float*)d_in[9];
    const float* g3 = (const float*)d_in[10];
    const float* g4 = (const float*)d_in[11];
    float* out = (float*)d_out;
    float* ws  = (float*)d_ws;

    const int T1 = in_sizes[4] / 3;   // 51200
    const int T2 = in_sizes[5] / 3;   // 12800
    const int T3 = in_sizes[6] / 3;   // 51200
    const int T4 = in_sizes[7] / 3;   // 12800
    const int BS = in_sizes[0] / DIM; // 1024

    // A: lh / lhT / ln2 (+ zero out)
    to_poincare_kernel<<<NPROX, 128, 0, stream>>>(lcas, ws, out);

    // B: the three distance matrices
    dist_kernel<<<BS / 4,    256, 0, stream>>>(z_s,          ws + OFF_LHT, ws + OFF_LN2, ws + OFF_D1);
    dist_kernel<<<NPROX / 4, 256, 0, stream>>>(ws + OFF_LH,  ws + OFF_LHT, ws + OFF_LN2, ws + OFF_D2);
    dist_kernel<<<BS / 4,    256, 0, stream>>>(t_s,          ws + OFF_LHT, ws + OFF_LN2, ws + OFF_D3);

    // C: the four ghhc terms (term2/term4 share D2)
    auto nb = [](int T) { int b = (T + 3) / 4; return b > 4096 ? 4096 : b; };
    ghhc_kernel<<<nb(T1), 256, 0, stream>>>(ws + OFF_D1, trip1, g1, T1, 1.0f / (float)T1, out);
    ghhc_kernel<<<nb(T2), 256, 0, stream>>>(ws + OFF_D2, trip2, g2, T2, 1.0f / (float)T2, out);
    ghhc_kernel<<<nb(T3), 256, 0, stream>>>(ws + OFF_D3, trip3, g3, T3, 1.0f / (float)T3, out);
    ghhc_kernel<<<nb(T4), 256, 0, stream>>>(ws + OFF_D2, trip4, g4, T4, 1.0f / (float)T4, out);
}

// Round 2
// 318.859 us; speedup vs baseline: 1.4207x; 1.4207x over previous
//
#include <hip/hip_runtime.h>
#include <cstddef>
#include <stdint.h>

#define HYP_C   0.1f
#define SQRT_C  0.31622776601683794f
#define CLIP_R  2.3f
#define MRG     0.1f
#define NPROX   256
#define DIM     128

// workspace layout (float offsets)
#define OFF_LH   0         // lh row-major      [256][128]
#define OFF_LHT  32768     // lh transposed     [128][256]
#define OFF_LN2  65536     // ||lh_m||^2        [256]
#define OFF_D1   65792     // dist(z, lh)       [1024][256]
#define OFF_D2   327936    // dist(lh, lh)      [256][256]
#define OFF_D3   393472    // dist(t, lh)       [1024][256]

// ---------------------------------------------------------------------------
// Kernel A: to_poincare(lcas) -> lh, lhT, ln2 ; also zero d_out
// ---------------------------------------------------------------------------
__global__ __launch_bounds__(128)
void to_poincare_kernel(const float* __restrict__ lcas,
                        float* __restrict__ ws,
                        float* __restrict__ out)
{
    const int row = blockIdx.x;
    const int k   = threadIdx.x;
    if (row == 0 && k == 0) out[0] = 0.0f;

    float v  = lcas[row * DIM + k];
    float ss = v * v;
    #pragma unroll
    for (int off = 32; off >= 1; off >>= 1)
        ss += __shfl_xor(ss, off, 64);
    __shared__ float wpart[2];
    if ((k & 63) == 0) wpart[k >> 6] = ss;
    __syncthreads();
    const float sumsq = wpart[0] + wpart[1];

    const float s1 = sqrtf(sumsq);
    const float xn = s1 + 1e-5f;
    const float f1 = fminf(1.0f, CLIP_R / xn);
    const float xn2 = fmaxf(f1 * s1, 1e-5f);
    const float th  = tanhf(SQRT_C * xn2);
    const float f2  = th / (SQRT_C * xn2);
    const float nr      = fmaxf(f2 * f1 * s1, 1e-5f);
    const float maxnorm = (1.0f - 1e-3f) / SQRT_C;
    const float f3      = (nr > maxnorm) ? (maxnorm / nr) : 1.0f;

    const float f  = f3 * f2 * f1;
    const float lv = f * v;
    ws[OFF_LH  + row * DIM + k]   = lv;
    ws[OFF_LHT + k * NPROX + row] = lv;
    if (k == 0) ws[OFF_LN2 + row] = f * f * sumsq;
}

// ---------------------------------------------------------------------------
// Kernel B: all three distance matrices in one launch.
// blocks [0,nb1) -> D1 rows of z ; [nb1,nb1+64) -> D2 rows of lh ;
// [nb1+64, nb1+64+nb1) -> D3 rows of t.   4 rows / block, 256 threads.
// ---------------------------------------------------------------------------
__global__ __launch_bounds__(256)
void dist_all_kernel(const float* __restrict__ z,
                     const float* __restrict__ t,
                     float* __restrict__ ws, int nb1)
{
    const float* lhT = ws + OFF_LHT;
    const float* ln2 = ws + OFF_LN2;

    int b = blockIdx.x;
    const float* X; float* Dout; int row0;
    if (b < nb1)            { X = z;            Dout = ws + OFF_D1; row0 = b * 4; }
    else if (b < nb1 + 64)  { X = ws + OFF_LH;  Dout = ws + OFF_D2; row0 = (b - nb1) * 4; }
    else                    { X = t;            Dout = ws + OFF_D3; row0 = (b - nb1 - 64) * 4; }

    __shared__ float xs[4][DIM];
    __shared__ float sx2[4];

    for (int idx = threadIdx.x; idx < 4 * DIM; idx += 256)
        xs[idx / DIM][idx % DIM] = X[row0 * DIM + idx];
    __syncthreads();

    const int wid  = threadIdx.x >> 6;
    const int lane = threadIdx.x & 63;
    {
        float a = xs[wid][lane];
        float c = xs[wid][lane + 64];
        float s = a * a + c * c;
        #pragma unroll
        for (int off = 32; off >= 1; off >>= 1)
            s += __shfl_xor(s, off, 64);
        if (lane == 0) sx2[wid] = s;
    }
    __syncthreads();

    const int m = threadIdx.x;
    float dot0 = 0.f, dot1 = 0.f, dot2 = 0.f, dot3 = 0.f;
    #pragma unroll 4
    for (int k = 0; k < DIM; ++k) {
        const float lv = lhT[k * NPROX + m];
        dot0 = fmaf(xs[0][k], lv, dot0);
        dot1 = fmaf(xs[1][k], lv, dot1);
        dot2 = fmaf(xs[2][k], lv, dot2);
        dot3 = fmaf(xs[3][k], lv, dot3);
    }

    const float y2 = ln2[m];
    float dots[4] = {dot0, dot1, dot2, dot3};
    #pragma unroll
    for (int r = 0; r < 4; ++r) {
        const float x2 = sx2[r];
        const float xy = -dots[r];
        const float a  = 1.0f + 2.0f * HYP_C * xy + HYP_C * y2;
        const float bb = 1.0f - HYP_C * x2;
        const float denom  = 1.0f + 2.0f * HYP_C * xy + HYP_C * HYP_C * x2 * y2;
        const float num_sq = a * a * x2 + 2.0f * a * bb * xy + bb * bb * y2;
        const float nrm = sqrtf(fmaxf(num_sq, 1e-12f)) / fabsf(denom + 1e-5f);
        float u = SQRT_C * nrm;
        u = fminf(fmaxf(u, -1.0f + 1e-5f), 1.0f - 1e-5f);
        const float d = (2.0f / SQRT_C) * (0.5f * (log1pf(u) - log1pf(-u)));
        Dout[(size_t)(row0 + r) * NPROX + m] = d;
    }
}

// ---------------------------------------------------------------------------
// Kernel C: all four ghhc terms fused. One wave per PAIR of triplets per
// iteration (2 triplets unrolled, 4 independent argmax chains interleaved).
// argmax carried as u64 key: (ordered-float-bits << 32) | (255 - col)
// => u64 max == argmax with first-index tie-break (jnp.argmax semantics).
// ---------------------------------------------------------------------------
__device__ __forceinline__ uint32_t fkey(float f) {
    uint32_t b = __float_as_uint(f);
    return (b & 0x80000000u) ? ~b : (b | 0x80000000u);
}

__device__ __forceinline__ float bcast_col(float4 v, int col) {
    const int comp = col & 3;
    float x = (comp == 0) ? v.x : (comp == 1) ? v.y : (comp == 2) ? v.z : v.w;
    return __shfl(x, col >> 2, 64);
}

__global__ __launch_bounds__(256)
void ghhc_fused_kernel(const float* __restrict__ Da, const float* __restrict__ Db,
                       const float* __restrict__ Dc, const float* __restrict__ Dd,
                       const int* __restrict__ ta, const int* __restrict__ tb,
                       const int* __restrict__ tc, const int* __restrict__ td,
                       const float* __restrict__ ga, const float* __restrict__ gb,
                       const float* __restrict__ gc, const float* __restrict__ gd,
                       int Ta, int Tb, int Tc, int Td,
                       float sa, float sb, float sc_, float sd,
                       float* __restrict__ out)
{
    const int lane = threadIdx.x & 63;
    const int gw   = (blockIdx.x << 2) | (threadIdx.x >> 6);
    const int nw   = gridDim.x << 2;
    const int b1 = Ta, b2 = Ta + Tb, b3 = Ta + Tb + Tc;
    const int P  = (b3 + Td) >> 1;           // all T are even
    float acc = 0.0f;

    for (int p = gw; p < P; p += nw) {
        const int t0 = p << 1;
        const float* D; const int* tr; const float* g; int Tt; float sc; int t;
        if (t0 < b1)      { D = Da; tr = ta; g = ga; Tt = Ta; sc = sa;  t = t0; }
        else if (t0 < b2) { D = Db; tr = tb; g = gb; Tt = Tb; sc = sb;  t = t0 - b1; }
        else if (t0 < b3) { D = Dc; tr = tc; g = gc; Tt = Tc; sc = sc_; t = t0 - b2; }
        else              { D = Dd; tr = td; g = gd; Tt = Td; sc = sd;  t = t0 - b3; }

        const int2 I2 = *(const int2*)(tr + t);
        const int2 J2 = *(const int2*)(tr + Tt + t);
        const int2 K2 = *(const int2*)(tr + 2 * Tt + t);
        const int I[2] = {I2.x, I2.y}, J[2] = {J2.x, J2.y}, Kk[2] = {K2.x, K2.y};

        float4 di[2], dj[2], dk[2];
        unsigned long long KA[2], KB[2];

        #pragma unroll
        for (int u = 0; u < 2; ++u) {
            di[u] = ((const float4*)(D + (size_t)I[u]  * NPROX))[lane];
            dj[u] = ((const float4*)(D + (size_t)J[u]  * NPROX))[lane];
            dk[u] = ((const float4*)(D + (size_t)Kk[u] * NPROX))[lane];
            const float4 G0 = ((const float4*)(g + (size_t)(t + u) * NPROX))[lane];
            const float4 G1 = ((const float4*)(g + ((size_t)Tt + t + u) * NPROX))[lane];

            const float m1x = fmaxf(di[u].x, dj[u].x), m1y = fmaxf(di[u].y, dj[u].y),
                        m1z = fmaxf(di[u].z, dj[u].z), m1w = fmaxf(di[u].w, dj[u].w);
            const int p0 = lane << 2;

            float s0 = (-m1x) / 0.1f + G0.x;
            float s1 = (-m1y) / 0.1f + G0.y;
            float s2 = (-m1z) / 0.1f + G0.z;
            float s3 = (-m1w) / 0.1f + G0.w;
            float bv = s0; int bi = p0;
            if (s1 > bv) { bv = s1; bi = p0 + 1; }
            if (s2 > bv) { bv = s2; bi = p0 + 2; }
            if (s3 > bv) { bv = s3; bi = p0 + 3; }
            KA[u] = ((unsigned long long)fkey(bv) << 32) | (unsigned)(255 - bi);

            const float m2x = fmaxf(dk[u].x, m1x), m2y = fmaxf(dk[u].y, m1y),
                        m2z = fmaxf(dk[u].z, m1z), m2w = fmaxf(dk[u].w, m1w);
            float u0 = (-m2x) / 0.1f + G1.x;
            float u1 = (-m2y) / 0.1f + G1.y;
            float u2 = (-m2z) / 0.1f + G1.z;
            float u3 = (-m2w) / 0.1f + G1.w;
            float cv = u0; int ci = p0;
            if (u1 > cv) { cv = u1; ci = p0 + 1; }
            if (u2 > cv) { cv = u2; ci = p0 + 2; }
            if (u3 > cv) { cv = u3; ci = p0 + 3; }
            KB[u] = ((unsigned long long)fkey(cv) << 32) | (unsigned)(255 - ci);
        }

        // 4 independent butterfly max chains, interleaved per stage
        #pragma unroll
        for (int off = 1; off < 64; off <<= 1) {
            unsigned long long q;
            q = __shfl_xor(KA[0], off, 64); if (q > KA[0]) KA[0] = q;
            q = __shfl_xor(KB[0], off, 64); if (q > KB[0]) KB[0] = q;
            q = __shfl_xor(KA[1], off, 64); if (q > KA[1]) KA[1] = q;
            q = __shfl_xor(KB[1], off, 64); if (q > KB[1]) KB[1] = q;
        }

        #pragma unroll
        for (int u = 0; u < 2; ++u) {
            const int A = 255 - (int)(KA[u] & 0xFFu);
            const int B = 255 - (int)(KB[u] & 0xFFu);
            if (A != B) {   // wave-uniform branch
                const float diA = bcast_col(di[u], A), diB = bcast_col(di[u], B);
                const float djA = bcast_col(dj[u], A), djB = bcast_col(dj[u], B);
                const float dkA = bcast_col(dk[u], A), dkB = bcast_col(dk[u], B);
                const float hc = fmaxf(diA - diB + MRG, 0.0f)
                               + fmaxf(djA - djB + MRG, 0.0f)
                               + fmaxf(dkB - dkA + MRG, 0.0f);
                acc += hc * sc;   // uniform across lanes; lane 0's copy is used
            }
        }
    }

    __shared__ float wsum[4];
    if (lane == 0) wsum[threadIdx.x >> 6] = acc;
    __syncthreads();
    if (threadIdx.x == 0)
        atomicAdd(out, wsum[0] + wsum[1] + wsum[2] + wsum[3]);
}

// ---------------------------------------------------------------------------
extern "C" void kernel_launch(void* const* d_in, const int* in_sizes, int n_in,
                              void* d_out, int out_size, void* d_ws, size_t ws_size,
                              hipStream_t stream)
{
    const float* z_s  = (const float*)d_in[0];
    const float* t_s  = (const float*)d_in[1];
    const float* lcas = (const float*)d_in[3];
    const int* trip1 = (const int*)d_in[4];
    const int* trip2 = (const int*)d_in[5];
    const int* trip3 = (const int*)d_in[6];
    const int* trip4 = (const int*)d_in[7];
    const float* g1 = (const float*)d_in[8];
    const float* g2 = (const float*)d_in[9];
    const float* g3 = (const float*)d_in[10];
    const float* g4 = (const float*)d_in[11];
    float* out = (float*)d_out;
    float* ws  = (float*)d_ws;

    const int T1 = in_sizes[4] / 3;   // 51200
    const int T2 = in_sizes[5] / 3;   // 12800
    const int T3 = in_sizes[6] / 3;   // 51200
    const int T4 = in_sizes[7] / 3;   // 12800
    const int BS = in_sizes[0] / DIM; // 1024
    const int nb1 = BS / 4;

    to_poincare_kernel<<<NPROX, 128, 0, stream>>>(lcas, ws, out);

    dist_all_kernel<<<2 * nb1 + 64, 256, 0, stream>>>(z_s, t_s, ws, nb1);

    ghhc_fused_kernel<<<4096, 256, 0, stream>>>(
        ws + OFF_D1, ws + OFF_D2, ws + OFF_D3, ws + OFF_D2,
        trip1, trip2, trip3, trip4,
        g1, g2, g3, g4,
        T1, T2, T3, T4,
        1.0f / (float)T1, 1.0f / (float)T2, 1.0f / (float)T3, 1.0f / (float)T4,
        out);
}

// Round 3
// 300.968 us; speedup vs baseline: 1.5051x; 1.0594x over previous
//
#include <hip/hip_runtime.h>
#include <cstddef>
#include <stdint.h>

#define HYP_C   0.1f
#define SQRT_C  0.31622776601683794f
#define CLIP_R  2.3f
#define MRG     0.1f
#define NPROX   256
#define DIM     128

// workspace layout (float offsets)
#define OFF_LH   0         // lh row-major      [256][128]
#define OFF_LHT  32768     // lh transposed     [128][256]
#define OFF_LN2  65536     // ||lh_m||^2        [256]
#define OFF_D1   65792     // dist(z, lh)       [1024][256]
#define OFF_D2   327936    // dist(lh, lh)      [256][256]
#define OFF_D3   393472    // dist(t, lh)       [1024][256]

// ---------------------------------------------------------------------------
// Kernel A: to_poincare(lcas) -> lh, lhT, ln2 ; also zero d_out
// ---------------------------------------------------------------------------
__global__ __launch_bounds__(128)
void to_poincare_kernel(const float* __restrict__ lcas,
                        float* __restrict__ ws,
                        float* __restrict__ out)
{
    const int row = blockIdx.x;
    const int k   = threadIdx.x;
    if (row == 0 && k == 0) out[0] = 0.0f;

    float v  = lcas[row * DIM + k];
    float ss = v * v;
    #pragma unroll
    for (int off = 32; off >= 1; off >>= 1)
        ss += __shfl_xor(ss, off, 64);
    __shared__ float wpart[2];
    if ((k & 63) == 0) wpart[k >> 6] = ss;
    __syncthreads();
    const float sumsq = wpart[0] + wpart[1];

    const float s1 = sqrtf(sumsq);
    const float xn = s1 + 1e-5f;
    const float f1 = fminf(1.0f, CLIP_R / xn);
    const float xn2 = fmaxf(f1 * s1, 1e-5f);
    const float th  = tanhf(SQRT_C * xn2);
    const float f2  = th / (SQRT_C * xn2);
    const float nr      = fmaxf(f2 * f1 * s1, 1e-5f);
    const float maxnorm = (1.0f - 1e-3f) / SQRT_C;
    const float f3      = (nr > maxnorm) ? (maxnorm / nr) : 1.0f;

    const float f  = f3 * f2 * f1;
    const float lv = f * v;
    ws[OFF_LH  + row * DIM + k]   = lv;
    ws[OFF_LHT + k * NPROX + row] = lv;
    if (k == 0) ws[OFF_LN2 + row] = f * f * sumsq;
}

// ---------------------------------------------------------------------------
// Kernel B: all three distance matrices in one launch. 4 rows/block.
// LDS reads vectorized to ds_read_b128 (broadcast, conflict-free).
// ---------------------------------------------------------------------------
__global__ __launch_bounds__(256)
void dist_all_kernel(const float* __restrict__ z,
                     const float* __restrict__ t,
                     float* __restrict__ ws, int nb1)
{
    const float* lhT = ws + OFF_LHT;
    const float* ln2 = ws + OFF_LN2;

    int b = blockIdx.x;
    const float* X; float* Dout; int row0;
    if (b < nb1)            { X = z;            Dout = ws + OFF_D1; row0 = b * 4; }
    else if (b < nb1 + 64)  { X = ws + OFF_LH;  Dout = ws + OFF_D2; row0 = (b - nb1) * 4; }
    else                    { X = t;            Dout = ws + OFF_D3; row0 = (b - nb1 - 64) * 4; }

    __shared__ float xs[4][DIM];
    __shared__ float sx2[4];

    for (int idx = threadIdx.x; idx < 4 * DIM; idx += 256)
        xs[idx / DIM][idx % DIM] = X[row0 * DIM + idx];
    __syncthreads();

    const int wid  = threadIdx.x >> 6;
    const int lane = threadIdx.x & 63;
    {
        float a = xs[wid][lane];
        float c = xs[wid][lane + 64];
        float s = a * a + c * c;
        #pragma unroll
        for (int off = 32; off >= 1; off >>= 1)
            s += __shfl_xor(s, off, 64);
        if (lane == 0) sx2[wid] = s;
    }
    __syncthreads();

    const int m = threadIdx.x;
    float dot0 = 0.f, dot1 = 0.f, dot2 = 0.f, dot3 = 0.f;
    #pragma unroll 8
    for (int k = 0; k < DIM; k += 4) {
        const float4 x0 = *(const float4*)&xs[0][k];
        const float4 x1 = *(const float4*)&xs[1][k];
        const float4 x2 = *(const float4*)&xs[2][k];
        const float4 x3 = *(const float4*)&xs[3][k];
        const float l0 = lhT[(k + 0) * NPROX + m];
        const float l1 = lhT[(k + 1) * NPROX + m];
        const float l2 = lhT[(k + 2) * NPROX + m];
        const float l3 = lhT[(k + 3) * NPROX + m];
        dot0 = fmaf(x0.x, l0, fmaf(x0.y, l1, fmaf(x0.z, l2, fmaf(x0.w, l3, dot0))));
        dot1 = fmaf(x1.x, l0, fmaf(x1.y, l1, fmaf(x1.z, l2, fmaf(x1.w, l3, dot1))));
        dot2 = fmaf(x2.x, l0, fmaf(x2.y, l1, fmaf(x2.z, l2, fmaf(x2.w, l3, dot2))));
        dot3 = fmaf(x3.x, l0, fmaf(x3.y, l1, fmaf(x3.z, l2, fmaf(x3.w, l3, dot3))));
    }

    const float y2 = ln2[m];
    float dots[4] = {dot0, dot1, dot2, dot3};
    #pragma unroll
    for (int r = 0; r < 4; ++r) {
        const float x2 = sx2[r];
        const float xy = -dots[r];
        const float a  = 1.0f + 2.0f * HYP_C * xy + HYP_C * y2;
        const float bb = 1.0f - HYP_C * x2;
        const float denom  = 1.0f + 2.0f * HYP_C * xy + HYP_C * HYP_C * x2 * y2;
        const float num_sq = a * a * x2 + 2.0f * a * bb * xy + bb * bb * y2;
        const float nrm = sqrtf(fmaxf(num_sq, 1e-12f)) / fabsf(denom + 1e-5f);
        float u = SQRT_C * nrm;
        u = fminf(fmaxf(u, -1.0f + 1e-5f), 1.0f - 1e-5f);
        const float d = (2.0f / SQRT_C) * (0.5f * (log1pf(u) - log1pf(-u)));
        Dout[(size_t)(row0 + r) * NPROX + m] = d;
    }
}

// ---------------------------------------------------------------------------
// Kernel C: fused ghhc. Half-wave per triplet (8 elems/lane, 32 lanes), the
// two triplets of a pair occupy the two halves of the wave. Value-only
// 5-stage butterfly; argmax index via ballot (first-index tie-break =
// lowest lane, and lowest component within lane via strict-> tournament).
// ---------------------------------------------------------------------------
__device__ __forceinline__ void tourn8(const float4 a, const float4 b,
                                       float& bv, int& bi)
{
    float v01 = a.x; int i01 = 0;
    if (a.y > v01) { v01 = a.y; i01 = 1; }
    float v23 = a.z; int i23 = 2;
    if (a.w > v23) { v23 = a.w; i23 = 3; }
    float v45 = b.x; int i45 = 4;
    if (b.y > v45) { v45 = b.y; i45 = 5; }
    float v67 = b.z; int i67 = 6;
    if (b.w > v67) { v67 = b.w; i67 = 7; }
    if (v23 > v01) { v01 = v23; i01 = i23; }
    if (v67 > v45) { v45 = v67; i45 = i67; }
    bv = v01; bi = i01;
    if (v45 > bv) { bv = v45; bi = i45; }
}

__device__ __forceinline__ int half_argmax(float lv, int bi, int base, int half)
{
    float hv = lv;
    #pragma unroll
    for (int off = 1; off <= 16; off <<= 1)
        hv = fmaxf(hv, __shfl_xor(hv, off, 64));     // stays within half
    const unsigned long long m = __ballot(lv == hv);
    const unsigned int m32 = (unsigned int)(m >> (half << 5));
    const int owner = (half << 5) + (__ffs(m32) - 1);
    return __shfl(base + bi, owner, 64);
}

__device__ __forceinline__ float do_pair(const float* __restrict__ D,
                                         const int* __restrict__ tr,
                                         const float* __restrict__ g,
                                         int Tt, int t, float sc,
                                         int half, int hl)
{
    const int tt = t + half;
    const int i = tr[tt];
    const int j = tr[Tt + tt];
    const int k = tr[2 * Tt + tt];

    const float4* Di = (const float4*)(D + (size_t)i * NPROX);
    const float4* Dj = (const float4*)(D + (size_t)j * NPROX);
    const float4* Dk = (const float4*)(D + (size_t)k * NPROX);
    const float4* G0 = (const float4*)(g + (size_t)tt * NPROX);
    const float4* G1 = (const float4*)(g + ((size_t)Tt + tt) * NPROX);
    const int q = hl * 2;
    const float4 di0 = Di[q], di1 = Di[q + 1];
    const float4 dj0 = Dj[q], dj1 = Dj[q + 1];
    const float4 dk0 = Dk[q], dk1 = Dk[q + 1];
    const float4 g00 = G0[q], g01 = G0[q + 1];
    const float4 g10 = G1[q], g11 = G1[q + 1];

    float4 m10, m11;
    m10.x = fmaxf(di0.x, dj0.x); m10.y = fmaxf(di0.y, dj0.y);
    m10.z = fmaxf(di0.z, dj0.z); m10.w = fmaxf(di0.w, dj0.w);
    m11.x = fmaxf(di1.x, dj1.x); m11.y = fmaxf(di1.y, dj1.y);
    m11.z = fmaxf(di1.z, dj1.z); m11.w = fmaxf(di1.w, dj1.w);

    float4 s0, s1;
    s0.x = fmaf(m10.x, -10.0f, g00.x); s0.y = fmaf(m10.y, -10.0f, g00.y);
    s0.z = fmaf(m10.z, -10.0f, g00.z); s0.w = fmaf(m10.w, -10.0f, g00.w);
    s1.x = fmaf(m11.x, -10.0f, g01.x); s1.y = fmaf(m11.y, -10.0f, g01.y);
    s1.z = fmaf(m11.z, -10.0f, g01.z); s1.w = fmaf(m11.w, -10.0f, g01.w);

    float bv; int bi;
    tourn8(s0, s1, bv, bi);
    const int A = half_argmax(bv, bi, hl * 8, half);

    float4 m20, m21;
    m20.x = fmaxf(dk0.x, m10.x); m20.y = fmaxf(dk0.y, m10.y);
    m20.z = fmaxf(dk0.z, m10.z); m20.w = fmaxf(dk0.w, m10.w);
    m21.x = fmaxf(dk1.x, m11.x); m21.y = fmaxf(dk1.y, m11.y);
    m21.z = fmaxf(dk1.z, m11.z); m21.w = fmaxf(dk1.w, m11.w);

    float4 u0, u1;
    u0.x = fmaf(m20.x, -10.0f, g10.x); u0.y = fmaf(m20.y, -10.0f, g10.y);
    u0.z = fmaf(m20.z, -10.0f, g10.z); u0.w = fmaf(m20.w, -10.0f, g10.w);
    u1.x = fmaf(m21.x, -10.0f, g11.x); u1.y = fmaf(m21.y, -10.0f, g11.y);
    u1.z = fmaf(m21.z, -10.0f, g11.z); u1.w = fmaf(m21.w, -10.0f, g11.w);

    float cv; int ci;
    tourn8(u0, u1, cv, ci);
    const int B = half_argmax(cv, ci, hl * 8, half);

    // L2-hot reloads (uniform address per half -> broadcast)
    const float diA = D[(size_t)i * NPROX + A], diB = D[(size_t)i * NPROX + B];
    const float djA = D[(size_t)j * NPROX + A], djB = D[(size_t)j * NPROX + B];
    const float dkA = D[(size_t)k * NPROX + A], dkB = D[(size_t)k * NPROX + B];
    const float hc = fmaxf(diA - diB + MRG, 0.0f)
                   + fmaxf(djA - djB + MRG, 0.0f)
                   + fmaxf(dkB - dkA + MRG, 0.0f);
    return (A != B) ? hc * sc : 0.0f;
}

__global__ __launch_bounds__(256)
void ghhc_fused_kernel(const float* __restrict__ Da, const float* __restrict__ Db,
                       const float* __restrict__ Dc, const float* __restrict__ Dd,
                       const int* __restrict__ ta, const int* __restrict__ tb,
                       const int* __restrict__ tc, const int* __restrict__ td,
                       const float* __restrict__ ga, const float* __restrict__ gb,
                       const float* __restrict__ gc, const float* __restrict__ gd,
                       int Ta, int Tb, int Tc, int Td,
                       float sa, float sb, float sc_, float sd,
                       float* __restrict__ out)
{
    const int lane = threadIdx.x & 63;
    const int half = lane >> 5;
    const int hl   = lane & 31;
    const int gw   = (blockIdx.x << 2) | (threadIdx.x >> 6);
    const int nw   = gridDim.x << 2;
    const int b1 = Ta, b2 = Ta + Tb, b3 = Ta + Tb + Tc;
    const int P  = (b3 + Td) >> 1;
    float acc = 0.0f;

    for (int p = gw; p < P; p += 2 * nw) {
        // pair 1
        {
            const int t0 = p << 1;
            const float* D; const int* tr; const float* g; int Tt; float sc; int t;
            if (t0 < b1)      { D = Da; tr = ta; g = ga; Tt = Ta; sc = sa;  t = t0; }
            else if (t0 < b2) { D = Db; tr = tb; g = gb; Tt = Tb; sc = sb;  t = t0 - b1; }
            else if (t0 < b3) { D = Dc; tr = tc; g = gc; Tt = Tc; sc = sc_; t = t0 - b2; }
            else              { D = Dd; tr = td; g = gd; Tt = Td; sc = sd;  t = t0 - b3; }
            acc += do_pair(D, tr, g, Tt, t, sc, half, hl);
        }
        // pair 2 (branch-free tail: recompute pair p with zeroed contribution)
        {
            const int p2v = p + nw;
            const bool ok = p2v < P;
            const int p2 = ok ? p2v : p;
            const int t0 = p2 << 1;
            const float* D; const int* tr; const float* g; int Tt; float sc; int t;
            if (t0 < b1)      { D = Da; tr = ta; g = ga; Tt = Ta; sc = sa;  t = t0; }
            else if (t0 < b2) { D = Db; tr = tb; g = gb; Tt = Tb; sc = sb;  t = t0 - b1; }
            else if (t0 < b3) { D = Dc; tr = tc; g = gc; Tt = Tc; sc = sc_; t = t0 - b2; }
            else              { D = Dd; tr = td; g = gd; Tt = Td; sc = sd;  t = t0 - b3; }
            const float v = do_pair(D, tr, g, Tt, t, sc, half, hl);
            acc += ok ? v : 0.0f;
        }
    }

    // combine the two halves (acc is uniform within each half)
    const float other = __shfl_xor(acc, 32, 64);
    const float tot = acc + other;
    __shared__ float wsum[4];
    if (lane == 0) wsum[threadIdx.x >> 6] = tot;
    __syncthreads();
    if (threadIdx.x == 0)
        atomicAdd(out, wsum[0] + wsum[1] + wsum[2] + wsum[3]);
}

// ---------------------------------------------------------------------------
extern "C" void kernel_launch(void* const* d_in, const int* in_sizes, int n_in,
                              void* d_out, int out_size, void* d_ws, size_t ws_size,
                              hipStream_t stream)
{
    const float* z_s  = (const float*)d_in[0];
    const float* t_s  = (const float*)d_in[1];
    const float* lcas = (const float*)d_in[3];
    const int* trip1 = (const int*)d_in[4];
    const int* trip2 = (const int*)d_in[5];
    const int* trip3 = (const int*)d_in[6];
    const int* trip4 = (const int*)d_in[7];
    const float* g1 = (const float*)d_in[8];
    const float* g2 = (const float*)d_in[9];
    const float* g3 = (const float*)d_in[10];
    const float* g4 = (const float*)d_in[11];
    float* out = (float*)d_out;
    float* ws  = (float*)d_ws;

    const int T1 = in_sizes[4] / 3;   // 51200
    const int T2 = in_sizes[5] / 3;   // 12800
    const int T3 = in_sizes[6] / 3;   // 51200
    const int T4 = in_sizes[7] / 3;   // 12800
    const int BS = in_sizes[0] / DIM; // 1024
    const int nb1 = BS / 4;

    to_poincare_kernel<<<NPROX, 128, 0, stream>>>(lcas, ws, out);

    dist_all_kernel<<<2 * nb1 + 64, 256, 0, stream>>>(z_s, t_s, ws, nb1);

    ghhc_fused_kernel<<<2048, 256, 0, stream>>>(
        ws + OFF_D1, ws + OFF_D2, ws + OFF_D3, ws + OFF_D2,
        trip1, trip2, trip3, trip4,
        g1, g2, g3, g4,
        T1, T2, T3, T4,
        1.0f / (float)T1, 1.0f / (float)T2, 1.0f / (float)T3, 1.0f / (float)T4,
        out);
}